// Round 12
// baseline (53315.662 us; speedup 1.0000x reference)
//
#include <hip/hip_runtime.h>
#include <math.h>

#define T_STEPS 2048
#define BATCH   64
#define HDIM    512
#define GDIM    2048   // 4*H
#define INDIM   256
#define HB_STEP (HDIM * BATCH)   // elements per timestep slot
#define GROUPS  4      // independent batch groups
#define WPG     8      // FAT dim-WGs per group per layer (1024 thr each)
#define BPG     16     // batches per group

typedef _Float16 f16x8 __attribute__((ext_vector_type(8)));
typedef _Float16 f16x4 __attribute__((ext_vector_type(4)));
typedef float    f32x4 __attribute__((ext_vector_type(4)));

__device__ __forceinline__ float sigf(float x) { return 1.0f / (1.0f + __expf(-x)); }
__device__ __forceinline__ float tanh_fast(float x) {
    return 1.0f - 2.0f / (__expf(2.0f * x) + 1.0f);   // saturates correctly
}

// ---------------------------------------------------------------------------
// fp32 -> fp16 conversion (weights once per launch; x once, 67 MB)
// ---------------------------------------------------------------------------
__global__ __launch_bounds__(256) void cvt_f16(const float* __restrict__ src,
                                               _Float16* __restrict__ dst, int n4)
{
    int i = blockIdx.x * 256 + threadIdx.x;
    if (i < n4) {
        float4 v = ((const float4*)src)[i];
        f16x4 h;
        h[0] = (_Float16)v.x; h[1] = (_Float16)v.y;
        h[2] = (_Float16)v.z; h[3] = (_Float16)v.w;
        ((f16x4*)dst)[i] = h;
    }
}

// ---------------------------------------------------------------------------
// Group-scoped wave poll, domain 8 (R5/R11-proven mechanism). Lanes 0..7
// each poll ONE 64B-strided flag of this group; __all combines. No
// __syncthreads in the loop. Flags hold absolute step numbers.
// ---------------------------------------------------------------------------
__device__ __forceinline__ void wait_flags_g8(const unsigned* __restrict__ flags,
                                              int g, unsigned tgt, int ln)
{
    const unsigned* p = flags + (size_t)(g * WPG + (ln & 7)) * 16;
    for (;;) {
        unsigned f = (ln < 8)
            ? __hip_atomic_load(p, __ATOMIC_RELAXED, __HIP_MEMORY_SCOPE_AGENT)
            : tgt;
        if (__all((int)(f >= tgt))) break;
    }
    __atomic_signal_fence(__ATOMIC_ACQUIRE);
}

// ---------------------------------------------------------------------------
// Fully-fused 2-layer MFMA LSTM, BATCH-GROUPED + FAT WGs. 64 blocks x 1024
// threads: bit5 = layer; wgl = g*8 + w. Each fat WG = 4 sub-WGs of 256
// threads, each sub running the R11-VERIFIED code path on dims
// j0 = w*64 + sub*16 (own gl/hsm LDS slice, identical per-thread math).
// Sync domain per group = 8 producers (was 32 in R11, 128 in R5); the 4
// subs coordinate via the on-CU HW barrier instead of LLC flags, and share
// A-fragment (x, h) lines through L1 -> ~4x less fabric gather traffic.
// Publish: each sub's wave 0 stores its 16-dim slice (R11 pattern), drains
// vmcnt in-wave; full-WG barrier; tid 0 stores the single per-WG flag.
// ---------------------------------------------------------------------------
__global__ __launch_bounds__(1024, 1) void lstm_fused(
    const _Float16* __restrict__ xh,     // [nsteps][64][256] fp16 (batch-major)
    const _Float16* __restrict__ Wf1h,   // W_hh1 [2048][512]
    const _Float16* __restrict__ Wf1i,   // W_ih1 [2048][256]
    const _Float16* __restrict__ Wf2i,   // W_ih2 [2048][512]
    const _Float16* __restrict__ Wf2h,   // W_hh2 [2048][512]
    const float* __restrict__ bih1, const float* __restrict__ bhh1,
    const float* __restrict__ bih2, const float* __restrict__ bhh2,
    _Float16* __restrict__ hb1,          // [nsteps+1][64][512] batch-major
    _Float16* __restrict__ hb2,
    float* __restrict__ c1,              // [512][64]
    float* __restrict__ c2,
    unsigned* __restrict__ flag1,        // [32] @ 64B stride (g*8+w)
    unsigned* __restrict__ flag2,
    int nsteps, unsigned t0a)
{
    __shared__ float    gl[4][4][16][20];   // [sub][gate][dim16][batch16], padded
    __shared__ _Float16 hsm[4][16][16];     // [sub][batch16][dim16]

    const int tid   = threadIdx.x;       // 0..1023
    const int sub   = tid >> 8;          // sub-WG 0..3
    const int stid  = tid & 255;         // thread within sub (R11's tid)
    const int layer = blockIdx.x >> 5;
    const int wgl   = blockIdx.x & 31;
    const int g     = wgl >> 3;          // batch group 0..3
    const int w     = wgl & 7;           // fat dim-WG 0..7
    const int j0    = w * 64 + sub * 16; // dim base (16 dims per sub)
    const int wv    = stid >> 6;         // wave within sub: dims j0+4wv..+3
    const int ln    = tid & 63;
    const int l16   = ln & 15;
    const int quad  = ln >> 4;
    const int grow  = (l16 >> 2) * HDIM + j0 + 4 * wv + (l16 & 3);
    const int d16   = stid >> 4;         // pointwise: dim within sub 0..15
    const int b16   = stid & 15;         // pointwise: batch within group
    const int dd    = j0 + d16;
    const int bu    = g * BPG + b16;
    const int arow  = g * BPG + l16;     // A-fragment batch row

    if (layer == 0) {
        // ------------------------- layer 1 -------------------------
        f16x8 Bh[16], Bx[8];
#pragma unroll
        for (int j = 0; j < 16; j++) {
            const uint4 u = *(const uint4*)&Wf1h[(size_t)grow * HDIM + j * 32 + quad * 8];
            Bh[j] = __builtin_bit_cast(f16x8, u);
        }
#pragma unroll
        for (int j = 0; j < 8; j++) {
            const uint4 u = *(const uint4*)&Wf1i[(size_t)grow * INDIM + j * 32 + quad * 8];
            Bx[j] = __builtin_bit_cast(f16x8, u);
        }
        float c_reg = c1[(size_t)dd * BATCH + bu];
        const float bi_ = bih1[0 * HDIM + dd] + bhh1[0 * HDIM + dd];
        const float bf_ = bih1[1 * HDIM + dd] + bhh1[1 * HDIM + dd];
        const float bg_ = bih1[2 * HDIM + dd] + bhh1[2 * HDIM + dd];
        const float bo_ = bih1[3 * HDIM + dd] + bhh1[3 * HDIM + dd];

        for (int t = 0; t < nsteps; t++) {
            f32x4 ax0 = {0.f, 0.f, 0.f, 0.f}, ax1 = {0.f, 0.f, 0.f, 0.f};

            // --- x contribution first (independent accumulators; no dep) ---
            {
                const _Float16* xp = xh + ((size_t)t * BATCH + arow) * INDIM
                                   + quad * 8;
                ulonglong2 ax[8];
#pragma unroll
                for (int j = 0; j < 8; j++)
                    ax[j] = *(const ulonglong2*)(xp + j * 32);
#pragma unroll
                for (int j = 0; j < 8; j += 2) {
                    ax0 = __builtin_amdgcn_mfma_f32_16x16x32_f16(
                        __builtin_bit_cast(f16x8, ax[j]),     Bx[j],     ax0, 0, 0, 0);
                    ax1 = __builtin_amdgcn_mfma_f32_16x16x32_f16(
                        __builtin_bit_cast(f16x8, ax[j + 1]), Bx[j + 1], ax1, 0, 0, 0);
                }
            }

            // --- critical path: W_hh1 @ h1[t] (group batches only) ---
            wait_flags_g8(flag1, g, t0a + (unsigned)t, ln);
            f32x4 ah0 = {0.f, 0.f, 0.f, 0.f}, ah1 = {0.f, 0.f, 0.f, 0.f};
            f32x4 ah2 = {0.f, 0.f, 0.f, 0.f}, ah3 = {0.f, 0.f, 0.f, 0.f};
            {
                const _Float16* hp = hb1 + (size_t)t * HB_STEP
                                   + (size_t)arow * HDIM + quad * 8;
                ulonglong2 a[16];
#pragma unroll
                for (int j = 0; j < 16; j++)
                    a[j] = *(const ulonglong2*)(hp + j * 32);
#pragma unroll
                for (int j = 0; j < 16; j += 4) {
                    ah0 = __builtin_amdgcn_mfma_f32_16x16x32_f16(
                        __builtin_bit_cast(f16x8, a[j]),     Bh[j],     ah0, 0, 0, 0);
                    ah1 = __builtin_amdgcn_mfma_f32_16x16x32_f16(
                        __builtin_bit_cast(f16x8, a[j + 1]), Bh[j + 1], ah1, 0, 0, 0);
                    ah2 = __builtin_amdgcn_mfma_f32_16x16x32_f16(
                        __builtin_bit_cast(f16x8, a[j + 2]), Bh[j + 2], ah2, 0, 0, 0);
                    ah3 = __builtin_amdgcn_mfma_f32_16x16x32_f16(
                        __builtin_bit_cast(f16x8, a[j + 3]), Bh[j + 3], ah3, 0, 0, 0);
                }
            }
            f32x4 d = (ax0 + ax1) + ((ah0 + ah1) + (ah2 + ah3));
            *(f32x4*)&gl[sub][l16 >> 2][4 * wv + (l16 & 3)][quad * 4] = d;
            __syncthreads();

            {
                float si = gl[sub][0][d16][b16] + bi_;
                float sf = gl[sub][1][d16][b16] + bf_;
                float sg = gl[sub][2][d16][b16] + bg_;
                float so = gl[sub][3][d16][b16] + bo_;
                c_reg = sigf(sf) * c_reg + sigf(si) * tanh_fast(sg);
                float h = sigf(so) * tanh_fast(c_reg);
                hsm[sub][b16][d16] = (_Float16)h;
            }
            __syncthreads();   // hsm ready; also protects gl before next D-write

            // --- packed publish (wave 0 of each sub): 16 x 8B quads ---
            if (stid < 64) {
                const int pb = stid >> 2, pd = stid & 3;   // batch16, dim-quad
                unsigned long long pk = *(const unsigned long long*)&hsm[sub][pb][pd * 4];
                unsigned long long* dst = (unsigned long long*)
                    (hb1 + (size_t)(t + 1) * HB_STEP
                         + (size_t)(g * BPG + pb) * HDIM + j0 + pd * 4);
                __hip_atomic_store(dst, pk, __ATOMIC_RELAXED, __HIP_MEMORY_SCOPE_AGENT);
                if (t == nsteps - 1) {   // carry slot for next chunk
                    unsigned long long* dst0 = (unsigned long long*)
                        (hb1 + (size_t)(g * BPG + pb) * HDIM + j0 + pd * 4);
                    __hip_atomic_store(dst0, pk, __ATOMIC_RELAXED, __HIP_MEMORY_SCOPE_AGENT);
                }
                asm volatile("s_waitcnt vmcnt(0)" ::: "memory");  // sub's h at LLC
            }
            __syncthreads();   // all 4 subs' publishes drained
            if (tid == 0)
                __hip_atomic_store(flag1 + (size_t)(g * WPG + w) * 16,
                                   t0a + (unsigned)t + 1u,
                                   __ATOMIC_RELAXED, __HIP_MEMORY_SCOPE_AGENT);
        }
        c1[(size_t)dd * BATCH + bu] = c_reg;
    } else {
        // ------------------------- layer 2 -------------------------
        f16x8 Bh[16], Bi[16];
#pragma unroll
        for (int j = 0; j < 16; j++) {
            const uint4 uh = *(const uint4*)&Wf2h[(size_t)grow * HDIM + j * 32 + quad * 8];
            Bh[j] = __builtin_bit_cast(f16x8, uh);
            const uint4 ui = *(const uint4*)&Wf2i[(size_t)grow * HDIM + j * 32 + quad * 8];
            Bi[j] = __builtin_bit_cast(f16x8, ui);
        }
        float c_reg = c2[(size_t)dd * BATCH + bu];
        const float bi_ = bih2[0 * HDIM + dd] + bhh2[0 * HDIM + dd];
        const float bf_ = bih2[1 * HDIM + dd] + bhh2[1 * HDIM + dd];
        const float bg_ = bih2[2 * HDIM + dd] + bhh2[2 * HDIM + dd];
        const float bo_ = bih2[3 * HDIM + dd] + bhh2[3 * HDIM + dd];

        for (int t = 0; t < nsteps; t++) {
            f32x4 ai0 = {0.f, 0.f, 0.f, 0.f}, ai1 = {0.f, 0.f, 0.f, 0.f};
            f32x4 ag0 = {0.f, 0.f, 0.f, 0.f}, ag1 = {0.f, 0.f, 0.f, 0.f};

            // --- W_ih2 @ h1[t+1] (group g's h1 only) ---
            wait_flags_g8(flag1, g, t0a + (unsigned)t + 1u, ln);
            {
                const _Float16* hp = hb1 + (size_t)(t + 1) * HB_STEP
                                   + (size_t)arow * HDIM + quad * 8;
                ulonglong2 a[16];
#pragma unroll
                for (int j = 0; j < 16; j++)
                    a[j] = *(const ulonglong2*)(hp + j * 32);
#pragma unroll
                for (int j = 0; j < 16; j += 2) {
                    ai0 = __builtin_amdgcn_mfma_f32_16x16x32_f16(
                        __builtin_bit_cast(f16x8, a[j]),     Bi[j],     ai0, 0, 0, 0);
                    ai1 = __builtin_amdgcn_mfma_f32_16x16x32_f16(
                        __builtin_bit_cast(f16x8, a[j + 1]), Bi[j + 1], ai1, 0, 0, 0);
                }
            }

            // --- critical path: W_hh2 @ h2[t] ---
            wait_flags_g8(flag2, g, t0a + (unsigned)t, ln);
            {
                const _Float16* hp = hb2 + (size_t)t * HB_STEP
                                   + (size_t)arow * HDIM + quad * 8;
                ulonglong2 a[16];
#pragma unroll
                for (int j = 0; j < 16; j++)
                    a[j] = *(const ulonglong2*)(hp + j * 32);
#pragma unroll
                for (int j = 0; j < 16; j += 2) {
                    ag0 = __builtin_amdgcn_mfma_f32_16x16x32_f16(
                        __builtin_bit_cast(f16x8, a[j]),     Bh[j],     ag0, 0, 0, 0);
                    ag1 = __builtin_amdgcn_mfma_f32_16x16x32_f16(
                        __builtin_bit_cast(f16x8, a[j + 1]), Bh[j + 1], ag1, 0, 0, 0);
                }
            }
            f32x4 d = (ai0 + ai1) + (ag0 + ag1);
            *(f32x4*)&gl[sub][l16 >> 2][4 * wv + (l16 & 3)][quad * 4] = d;
            __syncthreads();

            {
                float si = gl[sub][0][d16][b16] + bi_;
                float sf = gl[sub][1][d16][b16] + bf_;
                float sg = gl[sub][2][d16][b16] + bg_;
                float so = gl[sub][3][d16][b16] + bo_;
                c_reg = sigf(sf) * c_reg + sigf(si) * tanh_fast(sg);
                float h = sigf(so) * tanh_fast(c_reg);
                hsm[sub][b16][d16] = (_Float16)h;
            }
            __syncthreads();

            if (stid < 64) {
                const int pb = stid >> 2, pd = stid & 3;
                unsigned long long pk = *(const unsigned long long*)&hsm[sub][pb][pd * 4];
                unsigned long long* dst = (unsigned long long*)
                    (hb2 + (size_t)(t + 1) * HB_STEP
                         + (size_t)(g * BPG + pb) * HDIM + j0 + pd * 4);
                __hip_atomic_store(dst, pk, __ATOMIC_RELAXED, __HIP_MEMORY_SCOPE_AGENT);
                if (t == nsteps - 1) {
                    unsigned long long* dst0 = (unsigned long long*)
                        (hb2 + (size_t)(g * BPG + pb) * HDIM + j0 + pd * 4);
                    __hip_atomic_store(dst0, pk, __ATOMIC_RELAXED, __HIP_MEMORY_SCOPE_AGENT);
                }
                asm volatile("s_waitcnt vmcnt(0)" ::: "memory");
            }
            __syncthreads();
            if (tid == 0)
                __hip_atomic_store(flag2 + (size_t)(g * WPG + w) * 16,
                                   t0a + (unsigned)t + 1u,
                                   __ATOMIC_RELAXED, __HIP_MEMORY_SCOPE_AGENT);
        }
        c2[(size_t)dd * BATCH + bu] = c_reg;
    }
}

// ---------------------------------------------------------------------------
// out[t*64+b] = sigmoid(dot(Wout, h2[t][b][:]) + bout); h2 fp16 [t][b][512]
// (unchanged — batch-major layout preserved)
// ---------------------------------------------------------------------------
__global__ __launch_bounds__(256) void out_kernel(
    const _Float16* __restrict__ h2, const float* __restrict__ Wout,
    const float* __restrict__ bout, float* __restrict__ out)
{
    const int t = blockIdx.x;
    const int q = threadIdx.x >> 6, b = threadIdx.x & 63;
    const _Float16* base = &h2[(size_t)t * HB_STEP + (size_t)b * HDIM];
    float s = 0.0f;
#pragma unroll 8
    for (int k = q * 128; k < q * 128 + 128; k += 4) {
        const uint2 u = *(const uint2*)&base[k];
        f16x4 h = __builtin_bit_cast(f16x4, u);
        s += Wout[k] * (float)h[0] + Wout[k + 1] * (float)h[1]
           + Wout[k + 2] * (float)h[2] + Wout[k + 3] * (float)h[3];
    }
    __shared__ float red[4][64];
    red[q][b] = s;
    __syncthreads();
    if (q == 0) {
        float v = red[0][b] + red[1][b] + red[2][b] + red[3][b] + bout[0];
        out[t * BATCH + b] = sigf(v);
    }
}

// ---------------------------------------------------------------------------
static size_t req_bytes(int C) {
    return 65536                                      // flag arrays
         + 2ull * HDIM * BATCH * 4                    // c1, c2
         + 3ull * GDIM * HDIM * 2                     // Wf1h, Wf2i, Wf2h
         + (size_t)GDIM * INDIM * 2                   // Wf1i
         + (size_t)T_STEPS * BATCH * INDIM * 2        // xh (full sequence)
         + 2ull * (size_t)(C + 1) * BATCH * HDIM * 2; // hb1, hb2
}

extern "C" void kernel_launch(void* const* d_in, const int* in_sizes, int n_in,
                              void* d_out, int out_size, void* d_ws, size_t ws_size,
                              hipStream_t stream)
{
    const float* x    = (const float*)d_in[0];
    const float* Wih1 = (const float*)d_in[1];
    const float* Whh1 = (const float*)d_in[2];
    const float* bih1 = (const float*)d_in[3];
    const float* bhh1 = (const float*)d_in[4];
    const float* Wih2 = (const float*)d_in[5];
    const float* Whh2 = (const float*)d_in[6];
    const float* bih2 = (const float*)d_in[7];
    const float* bhh2 = (const float*)d_in[8];
    const float* Wout = (const float*)d_in[9];
    const float* bout = (const float*)d_in[10];
    float* out = (float*)d_out;

    int C = 8;
    const int cands[] = {2048, 1024, 512, 256, 128, 64, 32, 16, 8};
    for (int i = 0; i < 9; i++)
        if (req_bytes(cands[i]) <= ws_size) { C = cands[i]; break; }

    char* p = (char*)d_ws;
    unsigned*  flag1 = (unsigned*)p;                p += 32768;
    unsigned*  flag2 = (unsigned*)p;                p += 32768;
    float*     c1    = (float*)p;                   p += (size_t)HDIM * BATCH * 4;
    float*     c2    = (float*)p;                   p += (size_t)HDIM * BATCH * 4;
    _Float16*  Wf1h  = (_Float16*)p;                p += (size_t)GDIM * HDIM * 2;
    _Float16*  Wf1i  = (_Float16*)p;                p += (size_t)GDIM * INDIM * 2;
    _Float16*  Wf2i  = (_Float16*)p;                p += (size_t)GDIM * HDIM * 2;
    _Float16*  Wf2h  = (_Float16*)p;                p += (size_t)GDIM * HDIM * 2;
    _Float16*  xh    = (_Float16*)p;                p += (size_t)T_STEPS * BATCH * INDIM * 2;
    _Float16*  hb1   = (_Float16*)p;                p += (size_t)(C + 1) * BATCH * HDIM * 2;
    _Float16*  hb2   = (_Float16*)p;

    // zero flags + c-state (contiguous) and the two h carry slots
    hipMemsetAsync(flag1, 0, 65536 + 2ull * HDIM * BATCH * 4, stream);
    hipMemsetAsync(hb1, 0, (size_t)BATCH * HDIM * 2, stream);
    hipMemsetAsync(hb2, 0, (size_t)BATCH * HDIM * 2, stream);

    // fp16 conversions
    cvt_f16<<<dim3(GDIM * HDIM / 4 / 256), dim3(256), 0, stream>>>(Whh1, Wf1h, GDIM * HDIM / 4);
    cvt_f16<<<dim3(GDIM * INDIM / 4 / 256), dim3(256), 0, stream>>>(Wih1, Wf1i, GDIM * INDIM / 4);
    cvt_f16<<<dim3(GDIM * HDIM / 4 / 256), dim3(256), 0, stream>>>(Wih2, Wf2i, GDIM * HDIM / 4);
    cvt_f16<<<dim3(GDIM * HDIM / 4 / 256), dim3(256), 0, stream>>>(Whh2, Wf2h, GDIM * HDIM / 4);
    cvt_f16<<<dim3(T_STEPS * BATCH * INDIM / 4 / 256), dim3(256), 0, stream>>>(
        x, xh, T_STEPS * BATCH * INDIM / 4);

    const _Float16* h2r = hb2 + (size_t)HB_STEP;   // slots 1..C

    for (int t0 = 0; t0 < T_STEPS; t0 += C) {
        const _Float16* xc = xh + (size_t)t0 * BATCH * INDIM;
        unsigned t0a = (unsigned)t0;
        void* args[] = {(void*)&xc, (void*)&Wf1h, (void*)&Wf1i, (void*)&Wf2i,
                        (void*)&Wf2h, (void*)&bih1, (void*)&bhh1, (void*)&bih2,
                        (void*)&bhh2, (void*)&hb1, (void*)&hb2, (void*)&c1,
                        (void*)&c2, (void*)&flag1, (void*)&flag2, (void*)&C,
                        (void*)&t0a};
        hipLaunchCooperativeKernel((void*)lstm_fused, dim3(64), dim3(1024),
                                   args, 0, stream);

        out_kernel<<<dim3(C), dim3(256), 0, stream>>>(h2r, Wout, bout,
                                                      out + (size_t)t0 * BATCH);
    }

    (void)in_sizes; (void)n_in; (void)out_size;
}

// Round 13
// 18343.121 us; speedup vs baseline: 2.9066x; 2.9066x over previous
//
#include <hip/hip_runtime.h>
#include <math.h>

#define T_STEPS 2048
#define BATCH   64
#define HDIM    512
#define GDIM    2048   // 4*H
#define INDIM   256
#define HB_STEP (HDIM * BATCH)   // elements per timestep slot
#define GROUPS  4      // independent batch groups
#define WPG     16     // fat dim-WGs per group per layer (512 thr each)
#define BPG     16     // batches per group

typedef _Float16 f16x8 __attribute__((ext_vector_type(8)));
typedef _Float16 f16x4 __attribute__((ext_vector_type(4)));
typedef float    f32x4 __attribute__((ext_vector_type(4)));

__device__ __forceinline__ float sigf(float x) { return 1.0f / (1.0f + __expf(-x)); }
__device__ __forceinline__ float tanh_fast(float x) {
    return 1.0f - 2.0f / (__expf(2.0f * x) + 1.0f);   // saturates correctly
}

// ---------------------------------------------------------------------------
// fp32 -> fp16 conversion (weights once per launch; x once, 67 MB)
// ---------------------------------------------------------------------------
__global__ __launch_bounds__(256) void cvt_f16(const float* __restrict__ src,
                                               _Float16* __restrict__ dst, int n4)
{
    int i = blockIdx.x * 256 + threadIdx.x;
    if (i < n4) {
        float4 v = ((const float4*)src)[i];
        f16x4 h;
        h[0] = (_Float16)v.x; h[1] = (_Float16)v.y;
        h[2] = (_Float16)v.z; h[3] = (_Float16)v.w;
        ((f16x4*)dst)[i] = h;
    }
}

// ---------------------------------------------------------------------------
// Group-scoped wave poll, domain 16 (R5/R11-proven mechanism). Lanes 0..15
// each poll ONE 64B-strided flag of this group; __all combines. No
// __syncthreads in the loop. Flags hold absolute step numbers.
// R12 post-mortem: the 1024-thread variant died of a VGPR cliff (cap 64 <
// needed 128 -> full spill, 4.6x slower), NOT of the fat-WG idea itself.
// 512 threads = 8 waves/WG = 2 waves/SIMD -> VGPR budget 256, ours fits.
// ---------------------------------------------------------------------------
__device__ __forceinline__ void wait_flags_g16(const unsigned* __restrict__ flags,
                                               int g, unsigned tgt, int ln)
{
    const unsigned* p = flags + (size_t)(g * WPG + (ln & 15)) * 16;
    for (;;) {
        unsigned f = (ln < 16)
            ? __hip_atomic_load(p, __ATOMIC_RELAXED, __HIP_MEMORY_SCOPE_AGENT)
            : tgt;
        if (__all((int)(f >= tgt))) break;
    }
    __atomic_signal_fence(__ATOMIC_ACQUIRE);
}

// ---------------------------------------------------------------------------
// Fully-fused 2-layer MFMA LSTM, BATCH-GROUPED + 512-thread fat WGs.
// 128 blocks x 512 threads: bit6 = layer; wgl = g*16 + w. Each fat WG =
// 2 sub-WGs of 256 threads, each running the R11-VERIFIED code path on dims
// j0 = w*32 + sub*16 (own gl/hsm LDS slice, identical per-thread math).
// Sync domain per group = 16 producers (R11: 32, R5: 128); the 2 subs
// coordinate via the on-CU HW barrier and share A-fragment (x,h) lines in
// L1. Publish: each sub's wave 0 stores its 16-dim slice, drains vmcnt
// in-wave; full-WG barrier; tid 0 stores the single per-WG flag.
// ---------------------------------------------------------------------------
__global__ __launch_bounds__(512, 1) void lstm_fused(
    const _Float16* __restrict__ xh,     // [nsteps][64][256] fp16 (batch-major)
    const _Float16* __restrict__ Wf1h,   // W_hh1 [2048][512]
    const _Float16* __restrict__ Wf1i,   // W_ih1 [2048][256]
    const _Float16* __restrict__ Wf2i,   // W_ih2 [2048][512]
    const _Float16* __restrict__ Wf2h,   // W_hh2 [2048][512]
    const float* __restrict__ bih1, const float* __restrict__ bhh1,
    const float* __restrict__ bih2, const float* __restrict__ bhh2,
    _Float16* __restrict__ hb1,          // [nsteps+1][64][512] batch-major
    _Float16* __restrict__ hb2,
    float* __restrict__ c1,              // [512][64]
    float* __restrict__ c2,
    unsigned* __restrict__ flag1,        // [64] @ 64B stride (g*16+w)
    unsigned* __restrict__ flag2,
    int nsteps, unsigned t0a)
{
    __shared__ float    gl[2][4][16][20];   // [sub][gate][dim16][batch16]
    __shared__ _Float16 hsm[2][16][16];     // [sub][batch16][dim16]

    const int tid   = threadIdx.x;       // 0..511
    const int sub   = tid >> 8;          // sub-WG 0..1
    const int stid  = tid & 255;         // thread within sub (R11's tid)
    const int layer = blockIdx.x >> 6;
    const int wgl   = blockIdx.x & 63;
    const int g     = wgl >> 4;          // batch group 0..3
    const int w     = wgl & 15;          // fat dim-WG 0..15
    const int j0    = w * 32 + sub * 16; // dim base (16 dims per sub)
    const int wv    = stid >> 6;         // wave within sub: dims j0+4wv..+3
    const int ln    = tid & 63;
    const int l16   = ln & 15;
    const int quad  = ln >> 4;
    const int grow  = (l16 >> 2) * HDIM + j0 + 4 * wv + (l16 & 3);
    const int d16   = stid >> 4;         // pointwise: dim within sub 0..15
    const int b16   = stid & 15;         // pointwise: batch within group
    const int dd    = j0 + d16;
    const int bu    = g * BPG + b16;
    const int arow  = g * BPG + l16;     // A-fragment batch row

    if (layer == 0) {
        // ------------------------- layer 1 -------------------------
        f16x8 Bh[16], Bx[8];
#pragma unroll
        for (int j = 0; j < 16; j++) {
            const uint4 u = *(const uint4*)&Wf1h[(size_t)grow * HDIM + j * 32 + quad * 8];
            Bh[j] = __builtin_bit_cast(f16x8, u);
        }
#pragma unroll
        for (int j = 0; j < 8; j++) {
            const uint4 u = *(const uint4*)&Wf1i[(size_t)grow * INDIM + j * 32 + quad * 8];
            Bx[j] = __builtin_bit_cast(f16x8, u);
        }
        float c_reg = c1[(size_t)dd * BATCH + bu];
        const float bi_ = bih1[0 * HDIM + dd] + bhh1[0 * HDIM + dd];
        const float bf_ = bih1[1 * HDIM + dd] + bhh1[1 * HDIM + dd];
        const float bg_ = bih1[2 * HDIM + dd] + bhh1[2 * HDIM + dd];
        const float bo_ = bih1[3 * HDIM + dd] + bhh1[3 * HDIM + dd];

        for (int t = 0; t < nsteps; t++) {
            f32x4 ax0 = {0.f, 0.f, 0.f, 0.f}, ax1 = {0.f, 0.f, 0.f, 0.f};

            // --- x contribution first (independent accumulators; no dep) ---
            {
                const _Float16* xp = xh + ((size_t)t * BATCH + arow) * INDIM
                                   + quad * 8;
                ulonglong2 ax[8];
#pragma unroll
                for (int j = 0; j < 8; j++)
                    ax[j] = *(const ulonglong2*)(xp + j * 32);
#pragma unroll
                for (int j = 0; j < 8; j += 2) {
                    ax0 = __builtin_amdgcn_mfma_f32_16x16x32_f16(
                        __builtin_bit_cast(f16x8, ax[j]),     Bx[j],     ax0, 0, 0, 0);
                    ax1 = __builtin_amdgcn_mfma_f32_16x16x32_f16(
                        __builtin_bit_cast(f16x8, ax[j + 1]), Bx[j + 1], ax1, 0, 0, 0);
                }
            }

            // --- critical path: W_hh1 @ h1[t] (group batches only) ---
            wait_flags_g16(flag1, g, t0a + (unsigned)t, ln);
            f32x4 ah0 = {0.f, 0.f, 0.f, 0.f}, ah1 = {0.f, 0.f, 0.f, 0.f};
            f32x4 ah2 = {0.f, 0.f, 0.f, 0.f}, ah3 = {0.f, 0.f, 0.f, 0.f};
            {
                const _Float16* hp = hb1 + (size_t)t * HB_STEP
                                   + (size_t)arow * HDIM + quad * 8;
                ulonglong2 a[16];
#pragma unroll
                for (int j = 0; j < 16; j++)
                    a[j] = *(const ulonglong2*)(hp + j * 32);
#pragma unroll
                for (int j = 0; j < 16; j += 4) {
                    ah0 = __builtin_amdgcn_mfma_f32_16x16x32_f16(
                        __builtin_bit_cast(f16x8, a[j]),     Bh[j],     ah0, 0, 0, 0);
                    ah1 = __builtin_amdgcn_mfma_f32_16x16x32_f16(
                        __builtin_bit_cast(f16x8, a[j + 1]), Bh[j + 1], ah1, 0, 0, 0);
                    ah2 = __builtin_amdgcn_mfma_f32_16x16x32_f16(
                        __builtin_bit_cast(f16x8, a[j + 2]), Bh[j + 2], ah2, 0, 0, 0);
                    ah3 = __builtin_amdgcn_mfma_f32_16x16x32_f16(
                        __builtin_bit_cast(f16x8, a[j + 3]), Bh[j + 3], ah3, 0, 0, 0);
                }
            }
            f32x4 d = (ax0 + ax1) + ((ah0 + ah1) + (ah2 + ah3));
            *(f32x4*)&gl[sub][l16 >> 2][4 * wv + (l16 & 3)][quad * 4] = d;
            __syncthreads();

            {
                float si = gl[sub][0][d16][b16] + bi_;
                float sf = gl[sub][1][d16][b16] + bf_;
                float sg = gl[sub][2][d16][b16] + bg_;
                float so = gl[sub][3][d16][b16] + bo_;
                c_reg = sigf(sf) * c_reg + sigf(si) * tanh_fast(sg);
                float h = sigf(so) * tanh_fast(c_reg);
                hsm[sub][b16][d16] = (_Float16)h;
            }
            __syncthreads();   // hsm ready; also protects gl before next D-write

            // --- packed publish (wave 0 of each sub): 16 x 8B quads ---
            if (stid < 64) {
                const int pb = stid >> 2, pd = stid & 3;   // batch16, dim-quad
                unsigned long long pk = *(const unsigned long long*)&hsm[sub][pb][pd * 4];
                unsigned long long* dst = (unsigned long long*)
                    (hb1 + (size_t)(t + 1) * HB_STEP
                         + (size_t)(g * BPG + pb) * HDIM + j0 + pd * 4);
                __hip_atomic_store(dst, pk, __ATOMIC_RELAXED, __HIP_MEMORY_SCOPE_AGENT);
                if (t == nsteps - 1) {   // carry slot for next chunk
                    unsigned long long* dst0 = (unsigned long long*)
                        (hb1 + (size_t)(g * BPG + pb) * HDIM + j0 + pd * 4);
                    __hip_atomic_store(dst0, pk, __ATOMIC_RELAXED, __HIP_MEMORY_SCOPE_AGENT);
                }
                asm volatile("s_waitcnt vmcnt(0)" ::: "memory");  // sub's h at LLC
            }
            __syncthreads();   // both subs' publishes drained
            if (tid == 0)
                __hip_atomic_store(flag1 + (size_t)(g * WPG + w) * 16,
                                   t0a + (unsigned)t + 1u,
                                   __ATOMIC_RELAXED, __HIP_MEMORY_SCOPE_AGENT);
        }
        c1[(size_t)dd * BATCH + bu] = c_reg;
    } else {
        // ------------------------- layer 2 -------------------------
        f16x8 Bh[16], Bi[16];
#pragma unroll
        for (int j = 0; j < 16; j++) {
            const uint4 uh = *(const uint4*)&Wf2h[(size_t)grow * HDIM + j * 32 + quad * 8];
            Bh[j] = __builtin_bit_cast(f16x8, uh);
            const uint4 ui = *(const uint4*)&Wf2i[(size_t)grow * HDIM + j * 32 + quad * 8];
            Bi[j] = __builtin_bit_cast(f16x8, ui);
        }
        float c_reg = c2[(size_t)dd * BATCH + bu];
        const float bi_ = bih2[0 * HDIM + dd] + bhh2[0 * HDIM + dd];
        const float bf_ = bih2[1 * HDIM + dd] + bhh2[1 * HDIM + dd];
        const float bg_ = bih2[2 * HDIM + dd] + bhh2[2 * HDIM + dd];
        const float bo_ = bih2[3 * HDIM + dd] + bhh2[3 * HDIM + dd];

        for (int t = 0; t < nsteps; t++) {
            f32x4 ai0 = {0.f, 0.f, 0.f, 0.f}, ai1 = {0.f, 0.f, 0.f, 0.f};
            f32x4 ag0 = {0.f, 0.f, 0.f, 0.f}, ag1 = {0.f, 0.f, 0.f, 0.f};

            // --- W_ih2 @ h1[t+1] (group g's h1 only) ---
            wait_flags_g16(flag1, g, t0a + (unsigned)t + 1u, ln);
            {
                const _Float16* hp = hb1 + (size_t)(t + 1) * HB_STEP
                                   + (size_t)arow * HDIM + quad * 8;
                ulonglong2 a[16];
#pragma unroll
                for (int j = 0; j < 16; j++)
                    a[j] = *(const ulonglong2*)(hp + j * 32);
#pragma unroll
                for (int j = 0; j < 16; j += 2) {
                    ai0 = __builtin_amdgcn_mfma_f32_16x16x32_f16(
                        __builtin_bit_cast(f16x8, a[j]),     Bi[j],     ai0, 0, 0, 0);
                    ai1 = __builtin_amdgcn_mfma_f32_16x16x32_f16(
                        __builtin_bit_cast(f16x8, a[j + 1]), Bi[j + 1], ai1, 0, 0, 0);
                }
            }

            // --- critical path: W_hh2 @ h2[t] ---
            wait_flags_g16(flag2, g, t0a + (unsigned)t, ln);
            {
                const _Float16* hp = hb2 + (size_t)t * HB_STEP
                                   + (size_t)arow * HDIM + quad * 8;
                ulonglong2 a[16];
#pragma unroll
                for (int j = 0; j < 16; j++)
                    a[j] = *(const ulonglong2*)(hp + j * 32);
#pragma unroll
                for (int j = 0; j < 16; j += 2) {
                    ag0 = __builtin_amdgcn_mfma_f32_16x16x32_f16(
                        __builtin_bit_cast(f16x8, a[j]),     Bh[j],     ag0, 0, 0, 0);
                    ag1 = __builtin_amdgcn_mfma_f32_16x16x32_f16(
                        __builtin_bit_cast(f16x8, a[j + 1]), Bh[j + 1], ag1, 0, 0, 0);
                }
            }
            f32x4 d = (ai0 + ai1) + (ag0 + ag1);
            *(f32x4*)&gl[sub][l16 >> 2][4 * wv + (l16 & 3)][quad * 4] = d;
            __syncthreads();

            {
                float si = gl[sub][0][d16][b16] + bi_;
                float sf = gl[sub][1][d16][b16] + bf_;
                float sg = gl[sub][2][d16][b16] + bg_;
                float so = gl[sub][3][d16][b16] + bo_;
                c_reg = sigf(sf) * c_reg + sigf(si) * tanh_fast(sg);
                float h = sigf(so) * tanh_fast(c_reg);
                hsm[sub][b16][d16] = (_Float16)h;
            }
            __syncthreads();

            if (stid < 64) {
                const int pb = stid >> 2, pd = stid & 3;
                unsigned long long pk = *(const unsigned long long*)&hsm[sub][pb][pd * 4];
                unsigned long long* dst = (unsigned long long*)
                    (hb2 + (size_t)(t + 1) * HB_STEP
                         + (size_t)(g * BPG + pb) * HDIM + j0 + pd * 4);
                __hip_atomic_store(dst, pk, __ATOMIC_RELAXED, __HIP_MEMORY_SCOPE_AGENT);
                if (t == nsteps - 1) {
                    unsigned long long* dst0 = (unsigned long long*)
                        (hb2 + (size_t)(g * BPG + pb) * HDIM + j0 + pd * 4);
                    __hip_atomic_store(dst0, pk, __ATOMIC_RELAXED, __HIP_MEMORY_SCOPE_AGENT);
                }
                asm volatile("s_waitcnt vmcnt(0)" ::: "memory");
            }
            __syncthreads();
            if (tid == 0)
                __hip_atomic_store(flag2 + (size_t)(g * WPG + w) * 16,
                                   t0a + (unsigned)t + 1u,
                                   __ATOMIC_RELAXED, __HIP_MEMORY_SCOPE_AGENT);
        }
        c2[(size_t)dd * BATCH + bu] = c_reg;
    }
}

// ---------------------------------------------------------------------------
// out[t*64+b] = sigmoid(dot(Wout, h2[t][b][:]) + bout); h2 fp16 [t][b][512]
// (unchanged — batch-major layout preserved)
// ---------------------------------------------------------------------------
__global__ __launch_bounds__(256) void out_kernel(
    const _Float16* __restrict__ h2, const float* __restrict__ Wout,
    const float* __restrict__ bout, float* __restrict__ out)
{
    const int t = blockIdx.x;
    const int q = threadIdx.x >> 6, b = threadIdx.x & 63;
    const _Float16* base = &h2[(size_t)t * HB_STEP + (size_t)b * HDIM];
    float s = 0.0f;
#pragma unroll 8
    for (int k = q * 128; k < q * 128 + 128; k += 4) {
        const uint2 u = *(const uint2*)&base[k];
        f16x4 h = __builtin_bit_cast(f16x4, u);
        s += Wout[k] * (float)h[0] + Wout[k + 1] * (float)h[1]
           + Wout[k + 2] * (float)h[2] + Wout[k + 3] * (float)h[3];
    }
    __shared__ float red[4][64];
    red[q][b] = s;
    __syncthreads();
    if (q == 0) {
        float v = red[0][b] + red[1][b] + red[2][b] + red[3][b] + bout[0];
        out[t * BATCH + b] = sigf(v);
    }
}

// ---------------------------------------------------------------------------
static size_t req_bytes(int C) {
    return 65536                                      // flag arrays
         + 2ull * HDIM * BATCH * 4                    // c1, c2
         + 3ull * GDIM * HDIM * 2                     // Wf1h, Wf2i, Wf2h
         + (size_t)GDIM * INDIM * 2                   // Wf1i
         + (size_t)T_STEPS * BATCH * INDIM * 2        // xh (full sequence)
         + 2ull * (size_t)(C + 1) * BATCH * HDIM * 2; // hb1, hb2
}

extern "C" void kernel_launch(void* const* d_in, const int* in_sizes, int n_in,
                              void* d_out, int out_size, void* d_ws, size_t ws_size,
                              hipStream_t stream)
{
    const float* x    = (const float*)d_in[0];
    const float* Wih1 = (const float*)d_in[1];
    const float* Whh1 = (const float*)d_in[2];
    const float* bih1 = (const float*)d_in[3];
    const float* bhh1 = (const float*)d_in[4];
    const float* Wih2 = (const float*)d_in[5];
    const float* Whh2 = (const float*)d_in[6];
    const float* bih2 = (const float*)d_in[7];
    const float* bhh2 = (const float*)d_in[8];
    const float* Wout = (const float*)d_in[9];
    const float* bout = (const float*)d_in[10];
    float* out = (float*)d_out;

    int C = 8;
    const int cands[] = {2048, 1024, 512, 256, 128, 64, 32, 16, 8};
    for (int i = 0; i < 9; i++)
        if (req_bytes(cands[i]) <= ws_size) { C = cands[i]; break; }

    char* p = (char*)d_ws;
    unsigned*  flag1 = (unsigned*)p;                p += 32768;
    unsigned*  flag2 = (unsigned*)p;                p += 32768;
    float*     c1    = (float*)p;                   p += (size_t)HDIM * BATCH * 4;
    float*     c2    = (float*)p;                   p += (size_t)HDIM * BATCH * 4;
    _Float16*  Wf1h  = (_Float16*)p;                p += (size_t)GDIM * HDIM * 2;
    _Float16*  Wf1i  = (_Float16*)p;                p += (size_t)GDIM * INDIM * 2;
    _Float16*  Wf2i  = (_Float16*)p;                p += (size_t)GDIM * HDIM * 2;
    _Float16*  Wf2h  = (_Float16*)p;                p += (size_t)GDIM * HDIM * 2;
    _Float16*  xh    = (_Float16*)p;                p += (size_t)T_STEPS * BATCH * INDIM * 2;
    _Float16*  hb1   = (_Float16*)p;                p += (size_t)(C + 1) * BATCH * HDIM * 2;
    _Float16*  hb2   = (_Float16*)p;

    // zero flags + c-state (contiguous) and the two h carry slots
    hipMemsetAsync(flag1, 0, 65536 + 2ull * HDIM * BATCH * 4, stream);
    hipMemsetAsync(hb1, 0, (size_t)BATCH * HDIM * 2, stream);
    hipMemsetAsync(hb2, 0, (size_t)BATCH * HDIM * 2, stream);

    // fp16 conversions
    cvt_f16<<<dim3(GDIM * HDIM / 4 / 256), dim3(256), 0, stream>>>(Whh1, Wf1h, GDIM * HDIM / 4);
    cvt_f16<<<dim3(GDIM * INDIM / 4 / 256), dim3(256), 0, stream>>>(Wih1, Wf1i, GDIM * INDIM / 4);
    cvt_f16<<<dim3(GDIM * HDIM / 4 / 256), dim3(256), 0, stream>>>(Wih2, Wf2i, GDIM * HDIM / 4);
    cvt_f16<<<dim3(GDIM * HDIM / 4 / 256), dim3(256), 0, stream>>>(Whh2, Wf2h, GDIM * HDIM / 4);
    cvt_f16<<<dim3(T_STEPS * BATCH * INDIM / 4 / 256), dim3(256), 0, stream>>>(
        x, xh, T_STEPS * BATCH * INDIM / 4);

    const _Float16* h2r = hb2 + (size_t)HB_STEP;   // slots 1..C

    for (int t0 = 0; t0 < T_STEPS; t0 += C) {
        const _Float16* xc = xh + (size_t)t0 * BATCH * INDIM;
        unsigned t0a = (unsigned)t0;
        void* args[] = {(void*)&xc, (void*)&Wf1h, (void*)&Wf1i, (void*)&Wf2i,
                        (void*)&Wf2h, (void*)&bih1, (void*)&bhh1, (void*)&bih2,
                        (void*)&bhh2, (void*)&hb1, (void*)&hb2, (void*)&c1,
                        (void*)&c2, (void*)&flag1, (void*)&flag2, (void*)&C,
                        (void*)&t0a};
        hipLaunchCooperativeKernel((void*)lstm_fused, dim3(128), dim3(512),
                                   args, 0, stream);

        out_kernel<<<dim3(C), dim3(256), 0, stream>>>(h2r, Wout, bout,
                                                      out + (size_t)t0 * BATCH);
    }

    (void)in_sizes; (void)n_in; (void)out_size;
}

// Round 14
// 11494.509 us; speedup vs baseline: 4.6384x; 1.5958x over previous
//
#include <hip/hip_runtime.h>
#include <math.h>

#define T_STEPS 2048
#define BATCH   64
#define HDIM    512
#define GDIM    2048   // 4*H
#define INDIM   256
#define NBLK_RE 128    // recurrence workgroups PER LAYER
#define HB_STEP (HDIM * BATCH)   // elements per timestep slot
#define GROUPS  4      // independent batch groups
#define WPG     32     // dim-WGs per group per layer
#define BPG     16     // batches per group

typedef _Float16 f16x8 __attribute__((ext_vector_type(8)));
typedef _Float16 f16x4 __attribute__((ext_vector_type(4)));
typedef float    f32x4 __attribute__((ext_vector_type(4)));

__device__ __forceinline__ float sigf(float x) { return 1.0f / (1.0f + __expf(-x)); }
__device__ __forceinline__ float tanh_fast(float x) {
    return 1.0f - 2.0f / (__expf(2.0f * x) + 1.0f);   // saturates correctly
}

// ---------------------------------------------------------------------------
// fp32 -> fp16 conversion (weights once per launch; x once, 67 MB)
// ---------------------------------------------------------------------------
__global__ __launch_bounds__(256) void cvt_f16(const float* __restrict__ src,
                                               _Float16* __restrict__ dst, int n4)
{
    int i = blockIdx.x * 256 + threadIdx.x;
    if (i < n4) {
        float4 v = ((const float4*)src)[i];
        f16x4 h;
        h[0] = (_Float16)v.x; h[1] = (_Float16)v.y;
        h[2] = (_Float16)v.z; h[3] = (_Float16)v.w;
        ((f16x4*)dst)[i] = h;
    }
}

// ---------------------------------------------------------------------------
// Group-scoped wave poll (R5-proven mechanism, domain 128 -> 32 flags).
// Lanes 0..31 each poll ONE 64B-strided flag of this group; __all combines.
// No __syncthreads in the loop. Flags hold absolute step numbers.
// ---------------------------------------------------------------------------
__device__ __forceinline__ void wait_flags_grp(const unsigned* __restrict__ flags,
                                               int g, unsigned tgt, int ln)
{
    const unsigned* p = flags + (size_t)(g * WPG + (ln & 31)) * 16;
    for (;;) {
        unsigned f = (ln < 32)
            ? __hip_atomic_load(p, __ATOMIC_RELAXED, __HIP_MEMORY_SCOPE_AGENT)
            : tgt;
        if (__all((int)(f >= tgt))) break;
    }
    __atomic_signal_fence(__ATOMIC_ACQUIRE);
}

// ---------------------------------------------------------------------------
// Fully-fused 2-layer MFMA LSTM, BATCH-GROUPED (R11 — best verified:
// 11.38 ms, 5.42 us/step). 256 WGs: bit7 = layer; wgl = g*32 + w: group g
// (batches 16g..16g+15), dim-WG w (h-dims j0=16w..+15). Batches are
// independent in the recurrence, so the 4 groups are decoupled pipelines:
// sync domain = 32 producers, per-WG h gather = 16 KB/step. Per wave: dims
// j0+4wv..+3 x 4 gates = 16 gate rows x 16 batches, K=512 -> 16 MFMAs.
// VERIFIED PRIMITIVES: batch-major h [t][b][512], 16B fragment loads,
// hsm-staged 8B publish + vmcnt drain + flag, R5 wave poll.
// Post-R13 note: fat-WG variants (512/1024 thr) both regress — 8-16 wave
// barriers + fewer blocks/CU cost more than the domain shrink gains. This
// configuration is the measured optimum of the explored design space.
// ---------------------------------------------------------------------------
__global__ __launch_bounds__(256, 1) void lstm_fused(
    const _Float16* __restrict__ xh,     // [nsteps][64][256] fp16 (batch-major)
    const _Float16* __restrict__ Wf1h,   // W_hh1 [2048][512]
    const _Float16* __restrict__ Wf1i,   // W_ih1 [2048][256]
    const _Float16* __restrict__ Wf2i,   // W_ih2 [2048][512]
    const _Float16* __restrict__ Wf2h,   // W_hh2 [2048][512]
    const float* __restrict__ bih1, const float* __restrict__ bhh1,
    const float* __restrict__ bih2, const float* __restrict__ bhh2,
    _Float16* __restrict__ hb1,          // [nsteps+1][64][512] batch-major
    _Float16* __restrict__ hb2,
    float* __restrict__ c1,              // [512][64]
    float* __restrict__ c2,
    unsigned* __restrict__ flag1,        // [128] @ 64B stride (g*32+w)
    unsigned* __restrict__ flag2,
    int nsteps, unsigned t0a)
{
    __shared__ float    gl[4][16][20];   // [gate][dim16][batch16], padded
    __shared__ _Float16 hsm[16][16];     // [batch16][dim16]

    const int tid   = threadIdx.x;
    const int layer = blockIdx.x >> 7;
    const int wgl   = blockIdx.x & (NBLK_RE - 1);
    const int g     = wgl >> 5;          // batch group 0..3
    const int w     = wgl & 31;          // dim-WG 0..31
    const int j0    = w * 16;            // dim base (16 dims per WG)
    const int wv    = tid >> 6;          // wave: dims j0+4wv..+3
    const int ln    = tid & 63;
    const int l16   = ln & 15;
    const int quad  = ln >> 4;
    const int grow  = (l16 >> 2) * HDIM + j0 + 4 * wv + (l16 & 3);
    const int d16   = tid >> 4;          // pointwise: dim within WG 0..15
    const int b16   = tid & 15;          // pointwise: batch within group
    const int dd    = j0 + d16;
    const int bu    = g * BPG + b16;
    const int arow  = g * BPG + l16;     // A-fragment batch row

    if (layer == 0) {
        // ------------------------- layer 1 -------------------------
        f16x8 Bh[16], Bx[8];
#pragma unroll
        for (int j = 0; j < 16; j++) {
            const uint4 u = *(const uint4*)&Wf1h[(size_t)grow * HDIM + j * 32 + quad * 8];
            Bh[j] = __builtin_bit_cast(f16x8, u);
        }
#pragma unroll
        for (int j = 0; j < 8; j++) {
            const uint4 u = *(const uint4*)&Wf1i[(size_t)grow * INDIM + j * 32 + quad * 8];
            Bx[j] = __builtin_bit_cast(f16x8, u);
        }
        float c_reg = c1[(size_t)dd * BATCH + bu];
        const float bi_ = bih1[0 * HDIM + dd] + bhh1[0 * HDIM + dd];
        const float bf_ = bih1[1 * HDIM + dd] + bhh1[1 * HDIM + dd];
        const float bg_ = bih1[2 * HDIM + dd] + bhh1[2 * HDIM + dd];
        const float bo_ = bih1[3 * HDIM + dd] + bhh1[3 * HDIM + dd];

        for (int t = 0; t < nsteps; t++) {
            f32x4 ax0 = {0.f, 0.f, 0.f, 0.f}, ax1 = {0.f, 0.f, 0.f, 0.f};

            // --- x contribution first (independent accumulators; no dep) ---
            {
                const _Float16* xp = xh + ((size_t)t * BATCH + arow) * INDIM
                                   + quad * 8;
                ulonglong2 ax[8];
#pragma unroll
                for (int j = 0; j < 8; j++)
                    ax[j] = *(const ulonglong2*)(xp + j * 32);
#pragma unroll
                for (int j = 0; j < 8; j += 2) {
                    ax0 = __builtin_amdgcn_mfma_f32_16x16x32_f16(
                        __builtin_bit_cast(f16x8, ax[j]),     Bx[j],     ax0, 0, 0, 0);
                    ax1 = __builtin_amdgcn_mfma_f32_16x16x32_f16(
                        __builtin_bit_cast(f16x8, ax[j + 1]), Bx[j + 1], ax1, 0, 0, 0);
                }
            }

            // --- critical path: W_hh1 @ h1[t] (group batches only) ---
            wait_flags_grp(flag1, g, t0a + (unsigned)t, ln);
            f32x4 ah0 = {0.f, 0.f, 0.f, 0.f}, ah1 = {0.f, 0.f, 0.f, 0.f};
            f32x4 ah2 = {0.f, 0.f, 0.f, 0.f}, ah3 = {0.f, 0.f, 0.f, 0.f};
            {
                const _Float16* hp = hb1 + (size_t)t * HB_STEP
                                   + (size_t)arow * HDIM + quad * 8;
                ulonglong2 a[16];
#pragma unroll
                for (int j = 0; j < 16; j++)
                    a[j] = *(const ulonglong2*)(hp + j * 32);
#pragma unroll
                for (int j = 0; j < 16; j += 4) {
                    ah0 = __builtin_amdgcn_mfma_f32_16x16x32_f16(
                        __builtin_bit_cast(f16x8, a[j]),     Bh[j],     ah0, 0, 0, 0);
                    ah1 = __builtin_amdgcn_mfma_f32_16x16x32_f16(
                        __builtin_bit_cast(f16x8, a[j + 1]), Bh[j + 1], ah1, 0, 0, 0);
                    ah2 = __builtin_amdgcn_mfma_f32_16x16x32_f16(
                        __builtin_bit_cast(f16x8, a[j + 2]), Bh[j + 2], ah2, 0, 0, 0);
                    ah3 = __builtin_amdgcn_mfma_f32_16x16x32_f16(
                        __builtin_bit_cast(f16x8, a[j + 3]), Bh[j + 3], ah3, 0, 0, 0);
                }
            }
            f32x4 d = (ax0 + ax1) + ((ah0 + ah1) + (ah2 + ah3));
            // D: col=l16 -> gate row (gate=l16>>2, dim16=4wv+(l16&3));
            //    row=quad*4+r -> batch16
            *(f32x4*)&gl[l16 >> 2][4 * wv + (l16 & 3)][quad * 4] = d;
            __syncthreads();

            {
                float si = gl[0][d16][b16] + bi_;
                float sf = gl[1][d16][b16] + bf_;
                float sg = gl[2][d16][b16] + bg_;
                float so = gl[3][d16][b16] + bo_;
                c_reg = sigf(sf) * c_reg + sigf(si) * tanh_fast(sg);
                float h = sigf(so) * tanh_fast(c_reg);
                hsm[b16][d16] = (_Float16)h;
            }
            __syncthreads();   // hsm ready; also protects gl before next D-write

            // --- packed publish (wave 0): 16 batches x 8B quads ---
            if (tid < 64) {
                const int pb = tid >> 2, pd = tid & 3;     // batch16, dim-quad
                unsigned long long pk = *(const unsigned long long*)&hsm[pb][pd * 4];
                unsigned long long* dst = (unsigned long long*)
                    (hb1 + (size_t)(t + 1) * HB_STEP
                         + (size_t)(g * BPG + pb) * HDIM + j0 + pd * 4);
                __hip_atomic_store(dst, pk, __ATOMIC_RELAXED, __HIP_MEMORY_SCOPE_AGENT);
                if (t == nsteps - 1) {   // carry slot for next chunk
                    unsigned long long* dst0 = (unsigned long long*)
                        (hb1 + (size_t)(g * BPG + pb) * HDIM + j0 + pd * 4);
                    __hip_atomic_store(dst0, pk, __ATOMIC_RELAXED, __HIP_MEMORY_SCOPE_AGENT);
                }
                if (tid == 0) {
                    asm volatile("s_waitcnt vmcnt(0)" ::: "memory");  // h at LLC
                    __hip_atomic_store(flag1 + (size_t)wgl * 16, t0a + (unsigned)t + 1u,
                                       __ATOMIC_RELAXED, __HIP_MEMORY_SCOPE_AGENT);
                }
            }
        }
        c1[(size_t)dd * BATCH + bu] = c_reg;
    } else {
        // ------------------------- layer 2 -------------------------
        f16x8 Bh[16], Bi[16];
#pragma unroll
        for (int j = 0; j < 16; j++) {
            const uint4 uh = *(const uint4*)&Wf2h[(size_t)grow * HDIM + j * 32 + quad * 8];
            Bh[j] = __builtin_bit_cast(f16x8, uh);
            const uint4 ui = *(const uint4*)&Wf2i[(size_t)grow * HDIM + j * 32 + quad * 8];
            Bi[j] = __builtin_bit_cast(f16x8, ui);
        }
        float c_reg = c2[(size_t)dd * BATCH + bu];
        const float bi_ = bih2[0 * HDIM + dd] + bhh2[0 * HDIM + dd];
        const float bf_ = bih2[1 * HDIM + dd] + bhh2[1 * HDIM + dd];
        const float bg_ = bih2[2 * HDIM + dd] + bhh2[2 * HDIM + dd];
        const float bo_ = bih2[3 * HDIM + dd] + bhh2[3 * HDIM + dd];

        for (int t = 0; t < nsteps; t++) {
            f32x4 ai0 = {0.f, 0.f, 0.f, 0.f}, ai1 = {0.f, 0.f, 0.f, 0.f};
            f32x4 ag0 = {0.f, 0.f, 0.f, 0.f}, ag1 = {0.f, 0.f, 0.f, 0.f};

            // --- W_ih2 @ h1[t+1] (group g's h1 only) ---
            wait_flags_grp(flag1, g, t0a + (unsigned)t + 1u, ln);
            {
                const _Float16* hp = hb1 + (size_t)(t + 1) * HB_STEP
                                   + (size_t)arow * HDIM + quad * 8;
                ulonglong2 a[16];
#pragma unroll
                for (int j = 0; j < 16; j++)
                    a[j] = *(const ulonglong2*)(hp + j * 32);
#pragma unroll
                for (int j = 0; j < 16; j += 2) {
                    ai0 = __builtin_amdgcn_mfma_f32_16x16x32_f16(
                        __builtin_bit_cast(f16x8, a[j]),     Bi[j],     ai0, 0, 0, 0);
                    ai1 = __builtin_amdgcn_mfma_f32_16x16x32_f16(
                        __builtin_bit_cast(f16x8, a[j + 1]), Bi[j + 1], ai1, 0, 0, 0);
                }
            }

            // --- critical path: W_hh2 @ h2[t] ---
            wait_flags_grp(flag2, g, t0a + (unsigned)t, ln);
            {
                const _Float16* hp = hb2 + (size_t)t * HB_STEP
                                   + (size_t)arow * HDIM + quad * 8;
                ulonglong2 a[16];
#pragma unroll
                for (int j = 0; j < 16; j++)
                    a[j] = *(const ulonglong2*)(hp + j * 32);
#pragma unroll
                for (int j = 0; j < 16; j += 2) {
                    ag0 = __builtin_amdgcn_mfma_f32_16x16x32_f16(
                        __builtin_bit_cast(f16x8, a[j]),     Bh[j],     ag0, 0, 0, 0);
                    ag1 = __builtin_amdgcn_mfma_f32_16x16x32_f16(
                        __builtin_bit_cast(f16x8, a[j + 1]), Bh[j + 1], ag1, 0, 0, 0);
                }
            }
            f32x4 d = (ai0 + ai1) + (ag0 + ag1);
            *(f32x4*)&gl[l16 >> 2][4 * wv + (l16 & 3)][quad * 4] = d;
            __syncthreads();

            {
                float si = gl[0][d16][b16] + bi_;
                float sf = gl[1][d16][b16] + bf_;
                float sg = gl[2][d16][b16] + bg_;
                float so = gl[3][d16][b16] + bo_;
                c_reg = sigf(sf) * c_reg + sigf(si) * tanh_fast(sg);
                float h = sigf(so) * tanh_fast(c_reg);
                hsm[b16][d16] = (_Float16)h;
            }
            __syncthreads();

            if (tid < 64) {
                const int pb = tid >> 2, pd = tid & 3;
                unsigned long long pk = *(const unsigned long long*)&hsm[pb][pd * 4];
                unsigned long long* dst = (unsigned long long*)
                    (hb2 + (size_t)(t + 1) * HB_STEP
                         + (size_t)(g * BPG + pb) * HDIM + j0 + pd * 4);
                __hip_atomic_store(dst, pk, __ATOMIC_RELAXED, __HIP_MEMORY_SCOPE_AGENT);
                if (t == nsteps - 1) {
                    unsigned long long* dst0 = (unsigned long long*)
                        (hb2 + (size_t)(g * BPG + pb) * HDIM + j0 + pd * 4);
                    __hip_atomic_store(dst0, pk, __ATOMIC_RELAXED, __HIP_MEMORY_SCOPE_AGENT);
                }
                if (tid == 0) {
                    asm volatile("s_waitcnt vmcnt(0)" ::: "memory");
                    __hip_atomic_store(flag2 + (size_t)wgl * 16, t0a + (unsigned)t + 1u,
                                       __ATOMIC_RELAXED, __HIP_MEMORY_SCOPE_AGENT);
                }
            }
        }
        c2[(size_t)dd * BATCH + bu] = c_reg;
    }
}

// ---------------------------------------------------------------------------
// out[t*64+b] = sigmoid(dot(Wout, h2[t][b][:]) + bout); h2 fp16 [t][b][512]
// ---------------------------------------------------------------------------
__global__ __launch_bounds__(256) void out_kernel(
    const _Float16* __restrict__ h2, const float* __restrict__ Wout,
    const float* __restrict__ bout, float* __restrict__ out)
{
    const int t = blockIdx.x;
    const int q = threadIdx.x >> 6, b = threadIdx.x & 63;
    const _Float16* base = &h2[(size_t)t * HB_STEP + (size_t)b * HDIM];
    float s = 0.0f;
#pragma unroll 8
    for (int k = q * 128; k < q * 128 + 128; k += 4) {
        const uint2 u = *(const uint2*)&base[k];
        f16x4 h = __builtin_bit_cast(f16x4, u);
        s += Wout[k] * (float)h[0] + Wout[k + 1] * (float)h[1]
           + Wout[k + 2] * (float)h[2] + Wout[k + 3] * (float)h[3];
    }
    __shared__ float red[4][64];
    red[q][b] = s;
    __syncthreads();
    if (q == 0) {
        float v = red[0][b] + red[1][b] + red[2][b] + red[3][b] + bout[0];
        out[t * BATCH + b] = sigf(v);
    }
}

// ---------------------------------------------------------------------------
static size_t req_bytes(int C) {
    return 65536                                      // flag arrays
         + 2ull * HDIM * BATCH * 4                    // c1, c2
         + 3ull * GDIM * HDIM * 2                     // Wf1h, Wf2i, Wf2h
         + (size_t)GDIM * INDIM * 2                   // Wf1i
         + (size_t)T_STEPS * BATCH * INDIM * 2        // xh (full sequence)
         + 2ull * (size_t)(C + 1) * BATCH * HDIM * 2; // hb1, hb2
}

extern "C" void kernel_launch(void* const* d_in, const int* in_sizes, int n_in,
                              void* d_out, int out_size, void* d_ws, size_t ws_size,
                              hipStream_t stream)
{
    const float* x    = (const float*)d_in[0];
    const float* Wih1 = (const float*)d_in[1];
    const float* Whh1 = (const float*)d_in[2];
    const float* bih1 = (const float*)d_in[3];
    const float* bhh1 = (const float*)d_in[4];
    const float* Wih2 = (const float*)d_in[5];
    const float* Whh2 = (const float*)d_in[6];
    const float* bih2 = (const float*)d_in[7];
    const float* bhh2 = (const float*)d_in[8];
    const float* Wout = (const float*)d_in[9];
    const float* bout = (const float*)d_in[10];
    float* out = (float*)d_out;

    int C = 8;
    const int cands[] = {2048, 1024, 512, 256, 128, 64, 32, 16, 8};
    for (int i = 0; i < 9; i++)
        if (req_bytes(cands[i]) <= ws_size) { C = cands[i]; break; }

    char* p = (char*)d_ws;
    unsigned*  flag1 = (unsigned*)p;                p += 32768;
    unsigned*  flag2 = (unsigned*)p;                p += 32768;
    float*     c1    = (float*)p;                   p += (size_t)HDIM * BATCH * 4;
    float*     c2    = (float*)p;                   p += (size_t)HDIM * BATCH * 4;
    _Float16*  Wf1h  = (_Float16*)p;                p += (size_t)GDIM * HDIM * 2;
    _Float16*  Wf1i  = (_Float16*)p;                p += (size_t)GDIM * INDIM * 2;
    _Float16*  Wf2i  = (_Float16*)p;                p += (size_t)GDIM * HDIM * 2;
    _Float16*  Wf2h  = (_Float16*)p;                p += (size_t)GDIM * HDIM * 2;
    _Float16*  xh    = (_Float16*)p;                p += (size_t)T_STEPS * BATCH * INDIM * 2;
    _Float16*  hb1   = (_Float16*)p;                p += (size_t)(C + 1) * BATCH * HDIM * 2;
    _Float16*  hb2   = (_Float16*)p;

    // zero flags + c-state (contiguous) and the two h carry slots
    hipMemsetAsync(flag1, 0, 65536 + 2ull * HDIM * BATCH * 4, stream);
    hipMemsetAsync(hb1, 0, (size_t)BATCH * HDIM * 2, stream);
    hipMemsetAsync(hb2, 0, (size_t)BATCH * HDIM * 2, stream);

    // fp16 conversions
    cvt_f16<<<dim3(GDIM * HDIM / 4 / 256), dim3(256), 0, stream>>>(Whh1, Wf1h, GDIM * HDIM / 4);
    cvt_f16<<<dim3(GDIM * INDIM / 4 / 256), dim3(256), 0, stream>>>(Wih1, Wf1i, GDIM * INDIM / 4);
    cvt_f16<<<dim3(GDIM * HDIM / 4 / 256), dim3(256), 0, stream>>>(Wih2, Wf2i, GDIM * HDIM / 4);
    cvt_f16<<<dim3(GDIM * HDIM / 4 / 256), dim3(256), 0, stream>>>(Whh2, Wf2h, GDIM * HDIM / 4);
    cvt_f16<<<dim3(T_STEPS * BATCH * INDIM / 4 / 256), dim3(256), 0, stream>>>(
        x, xh, T_STEPS * BATCH * INDIM / 4);

    const _Float16* h2r = hb2 + (size_t)HB_STEP;   // slots 1..C

    for (int t0 = 0; t0 < T_STEPS; t0 += C) {
        const _Float16* xc = xh + (size_t)t0 * BATCH * INDIM;
        unsigned t0a = (unsigned)t0;
        void* args[] = {(void*)&xc, (void*)&Wf1h, (void*)&Wf1i, (void*)&Wf2i,
                        (void*)&Wf2h, (void*)&bih1, (void*)&bhh1, (void*)&bih2,
                        (void*)&bhh2, (void*)&hb1, (void*)&hb2, (void*)&c1,
                        (void*)&c2, (void*)&flag1, (void*)&flag2, (void*)&C,
                        (void*)&t0a};
        hipLaunchCooperativeKernel((void*)lstm_fused, dim3(2 * NBLK_RE), dim3(256),
                                   args, 0, stream);

        out_kernel<<<dim3(C), dim3(256), 0, stream>>>(h2r, Wout, bout,
                                                      out + (size_t)t0 * BATCH);
    }

    (void)in_sizes; (void)n_in; (void)out_size;
}